// Round 7
// baseline (162.482 us; speedup 1.0000x reference)
//
#include <hip/hip_runtime.h>

// out[h] = sum_e w_e * F[col_e][h],  w_e = values_e / (valsum(user_e) * U)
//
// 3-stage, no device-scope per-edge atomics, feature read EXACTLY once:
//  k_scatter:    bucket edges by col>>7 (782 buckets = 128-row/64KB feature
//                slices). LDS histogram + one global fetch_add per
//                (block,bucket) reserves a contiguous run; edge stored as ONE
//                u32: fp32 weight, low 7 mantissa bits = local row (2^-17 err).
//                EPB=1536: MUST be a multiple of 256 (round-6 bug: EPB=1600
//                made the 256-stride loops overrun into the next block's
//                edges -> 12% double-count) and of 32 (user-group alignment).
//                1042 blocks -> ~4/CU, fixes round-5's 8%-occupancy stall.
//  k_bucket_sum: one block per bucket. Pairs -> 128-float LDS weight array
//                (LDS atomics, ~16 adds/slot), then stream the 64KB slice
//                once, coalesced, scaling rows by LDS weights.
//  k3_final:     deterministic partial reduction.
// Fallback (ws too small / shape unexpected): round-2 path (known-good).

constexpr int EPB    = 1536;   // edges per scatter block; % 256 == 0, % 32 == 0
constexpr int BSHIFT = 7;      // 128 rows per bucket
constexpr int BROWS  = 1 << BSHIFT;
constexpr int CAP    = 2560;   // slots/bucket; mean 2046, wide headroom

// ---------------- fast path ----------------

__global__ void __launch_bounds__(256)
k_scatter(const float* __restrict__ values,
          const int*   __restrict__ col_ids,
          unsigned int* __restrict__ cursor,   // [nbuck], zeroed
          unsigned int* __restrict__ pairs,    // [nbuck*CAP]
          int E, int nbuck, float inv_u) {
    __shared__ unsigned int lhist[1024];
    __shared__ unsigned int lbase[1024];
    const int t = threadIdx.x;
    const int base_e = blockIdx.x * EPB;

    for (int b = t; b < nbuck; b += 256) lhist[b] = 0;
    __syncthreads();

    // pass 1: per-block bucket histogram (loop covers exactly EPB: EPB%256==0)
    for (int i = 0; i < EPB; i += 256) {
        int e = base_e + i + t;
        if (e < E) atomicAdd(&lhist[col_ids[e] >> BSHIFT], 1u);
    }
    __syncthreads();

    // reserve contiguous runs in each bucket region
    for (int b = t; b < nbuck; b += 256) {
        unsigned int cnt = lhist[b];
        lbase[b] = cnt ? atomicAdd(&cursor[b], cnt) : 0u;
        lhist[b] = 0;   // reuse as intra-block running cursor
    }
    __syncthreads();

    // pass 2: compute weight, write packed edge
    for (int i = 0; i < EPB; i += 256) {
        int e = base_e + i + t;
        float v = (e < E) ? values[e] : 0.0f;
        int   c = (e < E) ? col_ids[e] : 0;
        // valsum over the 32-lane user group (base_e+i is a multiple of 32,
        // so each 32-lane group == one user's 32 contiguous edges)
        float s = v;
        #pragma unroll
        for (int m = 1; m <= 16; m <<= 1) s += __shfl_xor(s, m);
        if (e < E) {
            float w = (v / s) * inv_u;
            int b = c >> BSHIFT;
            unsigned int r = atomicAdd(&lhist[b], 1u) + lbase[b];
            if (r < (unsigned)CAP) {
                unsigned int wb = __float_as_uint(w);
                pairs[(size_t)b * CAP + r] = (wb & ~127u) | (unsigned)(c & (BROWS - 1));
            }
        }
    }
}

__global__ void __launch_bounds__(256)
k_bucket_sum(const float4* __restrict__ feature4,
             const unsigned int* __restrict__ pairs,
             const unsigned int* __restrict__ cursor,
             float* __restrict__ partials,
             int n_items) {
    const int b = blockIdx.x;
    const int t = threadIdx.x;

    __shared__ float lw[BROWS];
    if (t < BROWS) lw[t] = 0.f;
    __syncthreads();

    // pairs -> per-row LDS weights (~16 adds/slot, trivial LDS-atomic contention)
    int n = (int)cursor[b]; if (n > CAP) n = CAP;
    const size_t pbase = (size_t)b * CAP;
    for (int j = t; j < n; j += 256) {
        unsigned int u = pairs[pbase + j];
        atomicAdd(&lw[u & (unsigned)(BROWS - 1)], __uint_as_float(u & ~127u));
    }
    __syncthreads();

    // stream the 64KB slice ONCE: 8 rows x 32 lanes(float4) per iter, 16 iters
    const int rowbase = b << BSHIFT;
    const int rsub = t >> 5;       // 0..7
    const int c4   = t & 31;       // float4 column
    float4 acc = make_float4(0.f, 0.f, 0.f, 0.f);
    #pragma unroll
    for (int r0 = 0; r0 < BROWS; r0 += 8) {
        int lr = r0 + rsub;
        int r  = rowbase + lr;
        if (r < n_items) {
            float  w = lw[lr];                       // broadcast within group
            float4 f = feature4[(size_t)r * 32 + c4];
            acc.x += w * f.x; acc.y += w * f.y;
            acc.z += w * f.z; acc.w += w * f.w;
        }
    }

    // reduce 8 groups -> 1 per block
    __shared__ float4 lds[256];
    lds[t] = acc;
    __syncthreads();
    #pragma unroll
    for (int st = 128; st >= 32; st >>= 1) {
        if (t < st) {
            float4 a = lds[t], c2 = lds[t + st];
            a.x += c2.x; a.y += c2.y; a.z += c2.z; a.w += c2.w;
            lds[t] = a;
        }
        __syncthreads();
    }
    if (t < 32) {
        float4 a = lds[t];
        float* p = &partials[(size_t)b * 128 + t * 4];
        p[0] = a.x; p[1] = a.y; p[2] = a.z; p[3] = a.w;
    }
}

// One block per h: stride over partial rows, LDS tree reduce. Deterministic.
__global__ void __launch_bounds__(256)
k3_final(const float* __restrict__ partials,
         float* __restrict__ out,
         int nparts) {
    const int h = blockIdx.x;
    const int t = threadIdx.x;
    float s = 0.f;
    for (int p = t; p < nparts; p += 256)
        s += partials[(size_t)p * 128 + h];
    __shared__ float lds[256];
    lds[t] = s;
    __syncthreads();
    #pragma unroll
    for (int st = 128; st >= 1; st >>= 1) {
        if (t < st) lds[t] += lds[t + st];
        __syncthreads();
    }
    if (t == 0) out[h] = lds[0];
}

// ---------------- fallback path (round-2, known-good) ----------------

__global__ void k1_item_weights(const float* __restrict__ values,
                                const int*   __restrict__ col_ids,
                                float* __restrict__ item_w,
                                int E, float inv_u) {
    int e = blockIdx.x * blockDim.x + threadIdx.x;
    float v = (e < E) ? values[e] : 0.0f;
    float s = v;
    #pragma unroll
    for (int m = 1; m <= 16; m <<= 1) s += __shfl_xor(s, m);
    if (e < E) atomicAdd(&item_w[col_ids[e]], (v / s) * inv_u);
}

__global__ void __launch_bounds__(256)
k2_weighted_sum(const float4* __restrict__ feature4,
                const float*  __restrict__ item_w,
                float* __restrict__ partials,
                int n_items) {
    const int t    = threadIdx.x;
    const int rsub = t >> 5;
    const int c4   = t & 31;
    float4 acc = make_float4(0.f, 0.f, 0.f, 0.f);
    for (int r0 = blockIdx.x * 8; r0 < n_items; r0 += gridDim.x * 8) {
        int r = r0 + rsub;
        if (r < n_items) {
            float  w = item_w[r];
            float4 f = feature4[(size_t)r * 32 + c4];
            acc.x += w * f.x; acc.y += w * f.y;
            acc.z += w * f.z; acc.w += w * f.w;
        }
    }
    __shared__ float4 lds[256];
    lds[t] = acc;
    __syncthreads();
    #pragma unroll
    for (int st = 128; st >= 32; st >>= 1) {
        if (t < st) {
            float4 a = lds[t], c2 = lds[t + st];
            a.x += c2.x; a.y += c2.y; a.z += c2.z; a.w += c2.w;
            lds[t] = a;
        }
        __syncthreads();
    }
    if (t < 32) {
        float4 a = lds[t];
        float* p = &partials[(size_t)blockIdx.x * 128 + t * 4];
        p[0] = a.x; p[1] = a.y; p[2] = a.z; p[3] = a.w;
    }
}

// ---------------- launch ----------------

extern "C" void kernel_launch(void* const* d_in, const int* in_sizes, int n_in,
                              void* d_out, int out_size, void* d_ws, size_t ws_size,
                              hipStream_t stream) {
    const float* feature = (const float*)d_in[0];
    const float* values  = (const float*)d_in[1];
    // d_in[2] = row_ids (unused: repeat(arange(U),32) structure exploited)
    const int*   col_ids = (const int*)d_in[3];

    const int E       = in_sizes[1];         // 1,600,000
    const int H       = out_size;            // 128
    const int n_items = in_sizes[0] / H;     // 100,000
    const int n_users = E / 32;
    const float inv_u = 1.0f / (float)n_users;

    const int nbuck = (n_items + BROWS - 1) >> BSHIFT;   // 782

    // fast-path ws layout
    const size_t cursor_off = 0;
    const size_t pairs_off  = 4096;
    const size_t pairs_b    = (size_t)nbuck * CAP * 4;
    const size_t part_off   = pairs_off + ((pairs_b + 255) & ~(size_t)255);
    const size_t part_b     = (size_t)nbuck * 128 * 4;
    const size_t need       = part_off + part_b;

    const bool fast = (ws_size >= need) && (nbuck <= 1024) &&
                      (E / nbuck <= 2048) && (H == 128);

    if (fast) {
        unsigned int* cursor   = (unsigned int*)((char*)d_ws + cursor_off);
        unsigned int* pairs    = (unsigned int*)((char*)d_ws + pairs_off);
        float*        partials = (float*)((char*)d_ws + part_off);

        hipMemsetAsync(cursor, 0, (size_t)nbuck * 4, stream);
        k_scatter<<<(E + EPB - 1) / EPB, 256, 0, stream>>>(values, col_ids, cursor,
                                                           pairs, E, nbuck, inv_u);
        k_bucket_sum<<<nbuck, 256, 0, stream>>>((const float4*)feature, pairs,
                                                cursor, partials, n_items);
        k3_final<<<H, 256, 0, stream>>>(partials, (float*)d_out, nbuck);
    } else {
        float* item_w   = (float*)d_ws;            // [n_items]
        float* partials = item_w + n_items;        // [1024*128]
        hipMemsetAsync(item_w, 0, (size_t)n_items * sizeof(float), stream);
        k1_item_weights<<<(E + 255) / 256, 256, 0, stream>>>(values, col_ids,
                                                             item_w, E, inv_u);
        k2_weighted_sum<<<1024, 256, 0, stream>>>((const float4*)feature, item_w,
                                                  partials, n_items);
        k3_final<<<H, 256, 0, stream>>>(partials, (float*)d_out, 1024);
    }
}

// Round 10
// 139.171 us; speedup vs baseline: 1.1675x; 1.1675x over previous
//
#include <hip/hip_runtime.h>

// out[h] = sum_e w_e * F[col_e][h],  w_e = values_e / (valsum(user_e) * U)
//
// 3-stage, no device-scope per-edge atomics, feature read EXACTLY once:
//  k_scatter:    bucket edges by col>>7 (782 buckets = 128-row/64KB feature
//                slices). LDS histogram + one global fetch_add per
//                (block,bucket) reserves a contiguous run; edge stored as ONE
//                u32: fp32 weight, low 7 mantissa bits = local row (2^-17 err).
//                1024-thread blocks, EPB=6144 (%1024==0: stride loops cover
//                exactly EPB -- round-6 lesson; %32==0: user-group alignment).
//                Long runs (~8 edges/bucket/block, round-5's 25MB WRITE) AND
//                high occupancy (16 waves/block, 2 blocks/CU possible) --
//                fixes round-7's short-run write amplification (46MB) and
//                round-5's 8% occupancy simultaneously.
//  k_bucket_sum: one block per bucket. Pairs -> 128-float LDS weight array
//                (LDS atomics, ~16 adds/slot), then stream the 64KB slice
//                once, coalesced, scaling rows by LDS weights.
//  k3_final:     deterministic partial reduction.
// Fallback (ws too small / shape unexpected): round-2 path (known-good).

constexpr int SCT_T  = 1024;   // k_scatter block size
constexpr int EPB    = 6144;   // edges per scatter block; % SCT_T == 0, % 32 == 0
constexpr int BSHIFT = 7;      // 128 rows per bucket
constexpr int BROWS  = 1 << BSHIFT;
constexpr int CAP    = 2560;   // slots/bucket; mean 2046, wide headroom

// ---------------- fast path ----------------

__global__ void __launch_bounds__(SCT_T)
k_scatter(const float* __restrict__ values,
          const int*   __restrict__ col_ids,
          unsigned int* __restrict__ cursor,   // [nbuck], zeroed
          unsigned int* __restrict__ pairs,    // [nbuck*CAP]
          int E, int nbuck, float inv_u) {
    __shared__ unsigned int lhist[1024];
    __shared__ unsigned int lbase[1024];
    const int t = threadIdx.x;
    const int base_e = blockIdx.x * EPB;

    for (int b = t; b < nbuck; b += SCT_T) lhist[b] = 0;
    __syncthreads();

    // pass 1: per-block bucket histogram (covers exactly EPB: EPB % SCT_T == 0)
    for (int i = 0; i < EPB; i += SCT_T) {
        int e = base_e + i + t;
        if (e < E) atomicAdd(&lhist[col_ids[e] >> BSHIFT], 1u);
    }
    __syncthreads();

    // reserve contiguous runs in each bucket region
    for (int b = t; b < nbuck; b += SCT_T) {
        unsigned int cnt = lhist[b];
        lbase[b] = cnt ? atomicAdd(&cursor[b], cnt) : 0u;
        lhist[b] = 0;   // reuse as intra-block running cursor
    }
    __syncthreads();

    // pass 2: compute weight, write packed edge
    for (int i = 0; i < EPB; i += SCT_T) {
        int e = base_e + i + t;
        float v = (e < E) ? values[e] : 0.0f;
        int   c = (e < E) ? col_ids[e] : 0;
        // valsum over the 32-lane user group (base_e+i is a multiple of 32,
        // so each 32-lane group == one user's 32 contiguous edges)
        float s = v;
        #pragma unroll
        for (int m = 1; m <= 16; m <<= 1) s += __shfl_xor(s, m);
        if (e < E) {
            float w = (v / s) * inv_u;
            int b = c >> BSHIFT;
            unsigned int r = atomicAdd(&lhist[b], 1u) + lbase[b];
            if (r < (unsigned)CAP) {
                unsigned int wb = __float_as_uint(w);
                pairs[(size_t)b * CAP + r] = (wb & ~127u) | (unsigned)(c & (BROWS - 1));
            }
        }
    }
}

__global__ void __launch_bounds__(256)
k_bucket_sum(const float4* __restrict__ feature4,
             const unsigned int* __restrict__ pairs,
             const unsigned int* __restrict__ cursor,
             float* __restrict__ partials,
             int n_items) {
    const int b = blockIdx.x;
    const int t = threadIdx.x;

    __shared__ float lw[BROWS];
    if (t < BROWS) lw[t] = 0.f;
    __syncthreads();

    // pairs -> per-row LDS weights (~16 adds/slot, trivial LDS-atomic contention)
    int n = (int)cursor[b]; if (n > CAP) n = CAP;
    const size_t pbase = (size_t)b * CAP;
    for (int j = t; j < n; j += 256) {
        unsigned int u = pairs[pbase + j];
        atomicAdd(&lw[u & (unsigned)(BROWS - 1)], __uint_as_float(u & ~127u));
    }
    __syncthreads();

    // stream the 64KB slice ONCE: 8 rows x 32 lanes(float4) per iter, 16 iters
    const int rowbase = b << BSHIFT;
    const int rsub = t >> 5;       // 0..7
    const int c4   = t & 31;       // float4 column
    float4 acc = make_float4(0.f, 0.f, 0.f, 0.f);
    #pragma unroll
    for (int r0 = 0; r0 < BROWS; r0 += 8) {
        int lr = r0 + rsub;
        int r  = rowbase + lr;
        if (r < n_items) {
            float  w = lw[lr];                       // broadcast within group
            float4 f = feature4[(size_t)r * 32 + c4];
            acc.x += w * f.x; acc.y += w * f.y;
            acc.z += w * f.z; acc.w += w * f.w;
        }
    }

    // reduce 8 groups -> 1 per block
    __shared__ float4 lds[256];
    lds[t] = acc;
    __syncthreads();
    #pragma unroll
    for (int st = 128; st >= 32; st >>= 1) {
        if (t < st) {
            float4 a = lds[t], c2 = lds[t + st];
            a.x += c2.x; a.y += c2.y; a.z += c2.z; a.w += c2.w;
            lds[t] = a;
        }
        __syncthreads();
    }
    if (t < 32) {
        float4 a = lds[t];
        float* p = &partials[(size_t)b * 128 + t * 4];
        p[0] = a.x; p[1] = a.y; p[2] = a.z; p[3] = a.w;
    }
}

// One block per h: stride over partial rows, LDS tree reduce. Deterministic.
__global__ void __launch_bounds__(256)
k3_final(const float* __restrict__ partials,
         float* __restrict__ out,
         int nparts) {
    const int h = blockIdx.x;
    const int t = threadIdx.x;
    float s = 0.f;
    for (int p = t; p < nparts; p += 256)
        s += partials[(size_t)p * 128 + h];
    __shared__ float lds[256];
    lds[t] = s;
    __syncthreads();
    #pragma unroll
    for (int st = 128; st >= 1; st >>= 1) {
        if (t < st) lds[t] += lds[t + st];
        __syncthreads();
    }
    if (t == 0) out[h] = lds[0];
}

// ---------------- fallback path (round-2, known-good) ----------------

__global__ void k1_item_weights(const float* __restrict__ values,
                                const int*   __restrict__ col_ids,
                                float* __restrict__ item_w,
                                int E, float inv_u) {
    int e = blockIdx.x * blockDim.x + threadIdx.x;
    float v = (e < E) ? values[e] : 0.0f;
    float s = v;
    #pragma unroll
    for (int m = 1; m <= 16; m <<= 1) s += __shfl_xor(s, m);
    if (e < E) atomicAdd(&item_w[col_ids[e]], (v / s) * inv_u);
}

__global__ void __launch_bounds__(256)
k2_weighted_sum(const float4* __restrict__ feature4,
                const float*  __restrict__ item_w,
                float* __restrict__ partials,
                int n_items) {
    const int t    = threadIdx.x;
    const int rsub = t >> 5;
    const int c4   = t & 31;
    float4 acc = make_float4(0.f, 0.f, 0.f, 0.f);
    for (int r0 = blockIdx.x * 8; r0 < n_items; r0 += gridDim.x * 8) {
        int r = r0 + rsub;
        if (r < n_items) {
            float  w = item_w[r];
            float4 f = feature4[(size_t)r * 32 + c4];
            acc.x += w * f.x; acc.y += w * f.y;
            acc.z += w * f.z; acc.w += w * f.w;
        }
    }
    __shared__ float4 lds[256];
    lds[t] = acc;
    __syncthreads();
    #pragma unroll
    for (int st = 128; st >= 32; st >>= 1) {
        if (t < st) {
            float4 a = lds[t], c2 = lds[t + st];
            a.x += c2.x; a.y += c2.y; a.z += c2.z; a.w += c2.w;
            lds[t] = a;
        }
        __syncthreads();
    }
    if (t < 32) {
        float4 a = lds[t];
        float* p = &partials[(size_t)blockIdx.x * 128 + t * 4];
        p[0] = a.x; p[1] = a.y; p[2] = a.z; p[3] = a.w;
    }
}

// ---------------- launch ----------------

extern "C" void kernel_launch(void* const* d_in, const int* in_sizes, int n_in,
                              void* d_out, int out_size, void* d_ws, size_t ws_size,
                              hipStream_t stream) {
    const float* feature = (const float*)d_in[0];
    const float* values  = (const float*)d_in[1];
    // d_in[2] = row_ids (unused: repeat(arange(U),32) structure exploited)
    const int*   col_ids = (const int*)d_in[3];

    const int E       = in_sizes[1];         // 1,600,000
    const int H       = out_size;            // 128
    const int n_items = in_sizes[0] / H;     // 100,000
    const int n_users = E / 32;
    const float inv_u = 1.0f / (float)n_users;

    const int nbuck = (n_items + BROWS - 1) >> BSHIFT;   // 782

    // fast-path ws layout
    const size_t cursor_off = 0;
    const size_t pairs_off  = 4096;
    const size_t pairs_b    = (size_t)nbuck * CAP * 4;
    const size_t part_off   = pairs_off + ((pairs_b + 255) & ~(size_t)255);
    const size_t part_b     = (size_t)nbuck * 128 * 4;
    const size_t need       = part_off + part_b;

    const bool fast = (ws_size >= need) && (nbuck <= 1024) &&
                      (E / nbuck <= 2048) && (H == 128);

    if (fast) {
        unsigned int* cursor   = (unsigned int*)((char*)d_ws + cursor_off);
        unsigned int* pairs    = (unsigned int*)((char*)d_ws + pairs_off);
        float*        partials = (float*)((char*)d_ws + part_off);

        hipMemsetAsync(cursor, 0, (size_t)nbuck * 4, stream);
        k_scatter<<<(E + EPB - 1) / EPB, SCT_T, 0, stream>>>(values, col_ids, cursor,
                                                             pairs, E, nbuck, inv_u);
        k_bucket_sum<<<nbuck, 256, 0, stream>>>((const float4*)feature, pairs,
                                                cursor, partials, n_items);
        k3_final<<<H, 256, 0, stream>>>(partials, (float*)d_out, nbuck);
    } else {
        float* item_w   = (float*)d_ws;            // [n_items]
        float* partials = item_w + n_items;        // [1024*128]
        hipMemsetAsync(item_w, 0, (size_t)n_items * sizeof(float), stream);
        k1_item_weights<<<(E + 255) / 256, 256, 0, stream>>>(values, col_ids,
                                                             item_w, E, inv_u);
        k2_weighted_sum<<<1024, 256, 0, stream>>>((const float4*)feature, item_w,
                                                  partials, n_items);
        k3_final<<<H, 256, 0, stream>>>(partials, (float*)d_out, 1024);
    }
}

// Round 11
// 131.385 us; speedup vs baseline: 1.2367x; 1.0593x over previous
//
#include <hip/hip_runtime.h>

// out[h] = sum_e w_e * F[col_e][h],  w_e = values_e / (valsum(user_e) * U)
//
// 3-stage, no device-scope per-edge atomics, feature read EXACTLY once:
//  k_scatter:    bucket edges by col>>7 (782 buckets = 128-row/64KB feature
//                slices). LDS histogram + one global fetch_add per
//                (block,bucket) reserves a contiguous run; edge stored as ONE
//                u32: fp32 weight, low 7 mantissa bits = local row (2^-17 err).
//                1024-thread blocks, EPB=6144, TWO edges per thread
//                (float2/int2): 16-lane subgroup == one user's 32 edges ->
//                valsum = 4-step shfl_xor; halves loop iters + loads for
//                latency-bound kernel (round-7: 3% VALUBusy, latency-stalled).
//                EPB % (2*SCT_T) == 0 (round-6 lesson: stride loops must
//                cover exactly EPB), % 32 == 0 (user-group alignment).
//  k_bucket_sum: one block per bucket. uint2 pairs -> 128-float LDS weight
//                array (LDS atomics), then stream the 64KB slice once,
//                2 rows/thread/iter (2 outstanding loads), coalesced.
//  k3_final:     deterministic partial reduction.
// Fallback (ws too small / shape unexpected): round-2 path (known-good).

constexpr int SCT_T  = 1024;   // k_scatter block size
constexpr int EPB    = 6144;   // edges per scatter block; % (2*SCT_T)==0, %32==0
constexpr int BSHIFT = 7;      // 128 rows per bucket
constexpr int BROWS  = 1 << BSHIFT;
constexpr int CAP    = 2560;   // slots/bucket; mean 2046, wide headroom

// ---------------- fast path ----------------

__global__ void __launch_bounds__(SCT_T)
k_scatter(const float2* __restrict__ values2,
          const int2*   __restrict__ col2,
          unsigned int* __restrict__ cursor,   // [nbuck], zeroed
          unsigned int* __restrict__ pairs,    // [nbuck*CAP]
          int E, int nbuck, float inv_u) {
    __shared__ unsigned int lhist[1024];
    __shared__ unsigned int lbase[1024];
    const int t = threadIdx.x;
    const int base_e = blockIdx.x * EPB;

    for (int b = t; b < nbuck; b += SCT_T) lhist[b] = 0;
    __syncthreads();

    // pass 1: per-block bucket histogram; 2 edges/thread (E is even: E=U*32)
    for (int i = 0; i < EPB; i += 2 * SCT_T) {
        int e0 = base_e + i + 2 * t;
        if (e0 < E) {
            int2 c = col2[e0 >> 1];
            atomicAdd(&lhist[c.x >> BSHIFT], 1u);
            atomicAdd(&lhist[c.y >> BSHIFT], 1u);
        }
    }
    __syncthreads();

    // reserve contiguous runs in each bucket region
    for (int b = t; b < nbuck; b += SCT_T) {
        unsigned int cnt = lhist[b];
        lbase[b] = cnt ? atomicAdd(&cursor[b], cnt) : 0u;
        lhist[b] = 0;   // reuse as intra-block running cursor
    }
    __syncthreads();

    // pass 2: weights + packed-edge writes. Lane l holds edges (2l,2l+1) of a
    // 2048-edge chunk: a 16-lane subgroup == one user's 32 contiguous edges,
    // so valsum = xor-reduce over masks 1,2,4,8 (stays within the subgroup).
    for (int i = 0; i < EPB; i += 2 * SCT_T) {
        int e0 = base_e + i + 2 * t;
        float2 v = (e0 < E) ? values2[e0 >> 1] : make_float2(0.f, 0.f);
        int2   c = (e0 < E) ? col2[e0 >> 1]    : make_int2(0, 0);
        float s = v.x + v.y;
        #pragma unroll
        for (int m = 1; m <= 8; m <<= 1) s += __shfl_xor(s, m);
        if (e0 < E) {
            float w0 = (v.x / s) * inv_u;
            float w1 = (v.y / s) * inv_u;
            int b0 = c.x >> BSHIFT;
            unsigned int r0 = atomicAdd(&lhist[b0], 1u) + lbase[b0];
            if (r0 < (unsigned)CAP)
                pairs[(size_t)b0 * CAP + r0] =
                    (__float_as_uint(w0) & ~127u) | (unsigned)(c.x & (BROWS - 1));
            int b1 = c.y >> BSHIFT;
            unsigned int r1 = atomicAdd(&lhist[b1], 1u) + lbase[b1];
            if (r1 < (unsigned)CAP)
                pairs[(size_t)b1 * CAP + r1] =
                    (__float_as_uint(w1) & ~127u) | (unsigned)(c.y & (BROWS - 1));
        }
    }
}

__global__ void __launch_bounds__(256)
k_bucket_sum(const float4* __restrict__ feature4,
             const unsigned int* __restrict__ pairs,
             const unsigned int* __restrict__ cursor,
             float* __restrict__ partials,
             int n_items) {
    const int b = blockIdx.x;
    const int t = threadIdx.x;

    __shared__ float lw[BROWS];
    if (t < BROWS) lw[t] = 0.f;
    __syncthreads();

    // pairs -> per-row LDS weights; uint2 loads (pbase even: CAP is even)
    int n = (int)cursor[b]; if (n > CAP) n = CAP;
    const size_t pbase = (size_t)b * CAP;
    const int m2 = n & ~1;
    for (int j2 = 2 * t; j2 < m2; j2 += 512) {
        uint2 u = *(const uint2*)(pairs + pbase + j2);
        atomicAdd(&lw[u.x & (unsigned)(BROWS - 1)], __uint_as_float(u.x & ~127u));
        atomicAdd(&lw[u.y & (unsigned)(BROWS - 1)], __uint_as_float(u.y & ~127u));
    }
    if ((n & 1) && t == 0) {
        unsigned int u = pairs[pbase + n - 1];
        atomicAdd(&lw[u & (unsigned)(BROWS - 1)], __uint_as_float(u & ~127u));
    }
    __syncthreads();

    // stream the 64KB slice ONCE: 2 rows/thread/iter, 8 iters, coalesced
    const int rowbase = b << BSHIFT;
    const int rsub = t >> 5;       // 0..7
    const int c4   = t & 31;       // float4 column
    float4 acc = make_float4(0.f, 0.f, 0.f, 0.f);
    #pragma unroll
    for (int r0 = 0; r0 < BROWS; r0 += 16) {
        int lrA = r0 + rsub,  lrB = lrA + 8;
        int rA  = rowbase + lrA, rB = rowbase + lrB;
        bool okA = rA < n_items, okB = rB < n_items;
        float4 fA = okA ? feature4[(size_t)rA * 32 + c4] : make_float4(0.f,0.f,0.f,0.f);
        float4 fB = okB ? feature4[(size_t)rB * 32 + c4] : make_float4(0.f,0.f,0.f,0.f);
        float  wA = okA ? lw[lrA] : 0.f;
        float  wB = okB ? lw[lrB] : 0.f;
        acc.x += wA * fA.x + wB * fB.x;
        acc.y += wA * fA.y + wB * fB.y;
        acc.z += wA * fA.z + wB * fB.z;
        acc.w += wA * fA.w + wB * fB.w;
    }

    // reduce 8 groups -> 1 per block
    __shared__ float4 lds[256];
    lds[t] = acc;
    __syncthreads();
    #pragma unroll
    for (int st = 128; st >= 32; st >>= 1) {
        if (t < st) {
            float4 a = lds[t], c2 = lds[t + st];
            a.x += c2.x; a.y += c2.y; a.z += c2.z; a.w += c2.w;
            lds[t] = a;
        }
        __syncthreads();
    }
    if (t < 32) {
        float4 a = lds[t];
        float* p = &partials[(size_t)b * 128 + t * 4];
        p[0] = a.x; p[1] = a.y; p[2] = a.z; p[3] = a.w;
    }
}

// One block per h: stride over partial rows, LDS tree reduce. Deterministic.
__global__ void __launch_bounds__(256)
k3_final(const float* __restrict__ partials,
         float* __restrict__ out,
         int nparts) {
    const int h = blockIdx.x;
    const int t = threadIdx.x;
    float s = 0.f;
    for (int p = t; p < nparts; p += 256)
        s += partials[(size_t)p * 128 + h];
    __shared__ float lds[256];
    lds[t] = s;
    __syncthreads();
    #pragma unroll
    for (int st = 128; st >= 1; st >>= 1) {
        if (t < st) lds[t] += lds[t + st];
        __syncthreads();
    }
    if (t == 0) out[h] = lds[0];
}

// ---------------- fallback path (round-2, known-good) ----------------

__global__ void k1_item_weights(const float* __restrict__ values,
                                const int*   __restrict__ col_ids,
                                float* __restrict__ item_w,
                                int E, float inv_u) {
    int e = blockIdx.x * blockDim.x + threadIdx.x;
    float v = (e < E) ? values[e] : 0.0f;
    float s = v;
    #pragma unroll
    for (int m = 1; m <= 16; m <<= 1) s += __shfl_xor(s, m);
    if (e < E) atomicAdd(&item_w[col_ids[e]], (v / s) * inv_u);
}

__global__ void __launch_bounds__(256)
k2_weighted_sum(const float4* __restrict__ feature4,
                const float*  __restrict__ item_w,
                float* __restrict__ partials,
                int n_items) {
    const int t    = threadIdx.x;
    const int rsub = t >> 5;
    const int c4   = t & 31;
    float4 acc = make_float4(0.f, 0.f, 0.f, 0.f);
    for (int r0 = blockIdx.x * 8; r0 < n_items; r0 += gridDim.x * 8) {
        int r = r0 + rsub;
        if (r < n_items) {
            float  w = item_w[r];
            float4 f = feature4[(size_t)r * 32 + c4];
            acc.x += w * f.x; acc.y += w * f.y;
            acc.z += w * f.z; acc.w += w * f.w;
        }
    }
    __shared__ float4 lds[256];
    lds[t] = acc;
    __syncthreads();
    #pragma unroll
    for (int st = 128; st >= 32; st >>= 1) {
        if (t < st) {
            float4 a = lds[t], c2 = lds[t + st];
            a.x += c2.x; a.y += c2.y; a.z += c2.z; a.w += c2.w;
            lds[t] = a;
        }
        __syncthreads();
    }
    if (t < 32) {
        float4 a = lds[t];
        float* p = &partials[(size_t)blockIdx.x * 128 + t * 4];
        p[0] = a.x; p[1] = a.y; p[2] = a.z; p[3] = a.w;
    }
}

// ---------------- launch ----------------

extern "C" void kernel_launch(void* const* d_in, const int* in_sizes, int n_in,
                              void* d_out, int out_size, void* d_ws, size_t ws_size,
                              hipStream_t stream) {
    const float* feature = (const float*)d_in[0];
    const float* values  = (const float*)d_in[1];
    // d_in[2] = row_ids (unused: repeat(arange(U),32) structure exploited)
    const int*   col_ids = (const int*)d_in[3];

    const int E       = in_sizes[1];         // 1,600,000
    const int H       = out_size;            // 128
    const int n_items = in_sizes[0] / H;     // 100,000
    const int n_users = E / 32;
    const float inv_u = 1.0f / (float)n_users;

    const int nbuck = (n_items + BROWS - 1) >> BSHIFT;   // 782

    // fast-path ws layout
    const size_t cursor_off = 0;
    const size_t pairs_off  = 4096;
    const size_t pairs_b    = (size_t)nbuck * CAP * 4;
    const size_t part_off   = pairs_off + ((pairs_b + 255) & ~(size_t)255);
    const size_t part_b     = (size_t)nbuck * 128 * 4;
    const size_t need       = part_off + part_b;

    const bool fast = (ws_size >= need) && (nbuck <= 1024) &&
                      (E / nbuck <= 2048) && (H == 128) && (E % 64 == 0);

    if (fast) {
        unsigned int* cursor   = (unsigned int*)((char*)d_ws + cursor_off);
        unsigned int* pairs    = (unsigned int*)((char*)d_ws + pairs_off);
        float*        partials = (float*)((char*)d_ws + part_off);

        hipMemsetAsync(cursor, 0, (size_t)nbuck * 4, stream);
        k_scatter<<<(E + EPB - 1) / EPB, SCT_T, 0, stream>>>(
            (const float2*)values, (const int2*)col_ids, cursor, pairs,
            E, nbuck, inv_u);
        k_bucket_sum<<<nbuck, 256, 0, stream>>>((const float4*)feature, pairs,
                                                cursor, partials, n_items);
        k3_final<<<H, 256, 0, stream>>>(partials, (float*)d_out, nbuck);
    } else {
        float* item_w   = (float*)d_ws;            // [n_items]
        float* partials = item_w + n_items;        // [1024*128]
        hipMemsetAsync(item_w, 0, (size_t)n_items * sizeof(float), stream);
        k1_item_weights<<<(E + 255) / 256, 256, 0, stream>>>(values, col_ids,
                                                             item_w, E, inv_u);
        k2_weighted_sum<<<1024, 256, 0, stream>>>((const float4*)feature, item_w,
                                                  partials, n_items);
        k3_final<<<H, 256, 0, stream>>>(partials, (float*)d_out, 1024);
    }
}